// Round 6
// baseline (3613.799 us; speedup 1.0000x reference)
//
#include <hip/hip_runtime.h>
#include <hip/hip_fp16.h>
#include <stdint.h>

#define NDIST 65536
#define NSTEPS 250

// ---- rotate: force single v_alignbit_b32 (rotl r == rotr 32-r) ----
#if __has_builtin(__builtin_amdgcn_alignbit)
#define ROTL32(x, r) __builtin_amdgcn_alignbit((x), (x), 32 - (r))
#else
#define ROTL32(x, r) (((x) << (r)) | ((x) >> (32 - (r))))
#endif

// Generic threefry (setup phase only; not perf-critical).
#define TF_ROUND(r) { x0 += x1; x1 = ROTL32(x1, r); x1 ^= x0; }
__device__ __forceinline__ uint2 threefry2x32(uint32_t ks0, uint32_t ks1, uint32_t ks2,
                                              uint32_t x0, uint32_t x1) {
  x0 += ks0; x1 += ks1;
  TF_ROUND(13) TF_ROUND(15) TF_ROUND(26) TF_ROUND(6)
  x0 += ks1; x1 += ks2 + 1u;
  TF_ROUND(17) TF_ROUND(29) TF_ROUND(16) TF_ROUND(24)
  x0 += ks2; x1 += ks0 + 2u;
  TF_ROUND(13) TF_ROUND(15) TF_ROUND(26) TF_ROUND(6)
  x0 += ks0; x1 += ks1 + 3u;
  TF_ROUND(17) TF_ROUND(29) TF_ROUND(16) TF_ROUND(24)
  x0 += ks1; x1 += ks2 + 4u;
  TF_ROUND(13) TF_ROUND(15) TF_ROUND(26) TF_ROUND(6)
  x0 += ks2; x1 += ks0 + 5u;
  return make_uint2(x0, x1);
}

// Verified stream (v5 PASS, absmax 0.03125):
//   keys[s] = TF((0,42),(0,s));  k2 = TF(keys[s],(0,1));
//   idx[p]  = (TF(k2,(0,p)).x ^ TF(k2,(0,p)).y) & 0xFFFF.
//
// Hot-loop draw: hand-scheduled, bit-identical (u32 adds associative mod 2^32):
//  - x0_init = 0 -> initial x0-inject is scalar (folded into round-1 add)
//  - mid-injection x0-adds fused with next round's x0+=x1 via v_add3
//  - injection constants (kz+1, kx+2, ...) precomputed on SALU
// ~72 VALU/draw vs ~143 inferred from v5's VALUBusy*dur.
__device__ __forceinline__ uint32_t draw_fold(
    uint32_t kx, uint32_t ky, uint32_t kz,
    uint32_t kz1, uint32_t kx2, uint32_t ky3, uint32_t kz4, uint32_t kx5,
    uint32_t p) {
  uint32_t x0, x1, t;
  x1 = p + ky;                                             // initial inject (x1)
  x0 = kx + x1; x1 = ROTL32(x1, 13) ^ x0;                  // r1 (x0 inject folded)
  x0 += x1;     x1 = ROTL32(x1, 15) ^ x0;                  // r2
  x0 += x1;     x1 = ROTL32(x1, 26) ^ x0;                  // r3
  x0 += x1;     x1 = ROTL32(x1,  6) ^ x0;                  // r4
  t = x1 + kz1; x0 = x0 + ky + t; x1 = ROTL32(t, 17) ^ x0; // inj1 + r5
  x0 += x1;     x1 = ROTL32(x1, 29) ^ x0;                  // r6
  x0 += x1;     x1 = ROTL32(x1, 16) ^ x0;                  // r7
  x0 += x1;     x1 = ROTL32(x1, 24) ^ x0;                  // r8
  t = x1 + kx2; x0 = x0 + kz + t; x1 = ROTL32(t, 13) ^ x0; // inj2 + r9
  x0 += x1;     x1 = ROTL32(x1, 15) ^ x0;                  // r10
  x0 += x1;     x1 = ROTL32(x1, 26) ^ x0;                  // r11
  x0 += x1;     x1 = ROTL32(x1,  6) ^ x0;                  // r12
  t = x1 + ky3; x0 = x0 + kx + t; x1 = ROTL32(t, 17) ^ x0; // inj3 + r13
  x0 += x1;     x1 = ROTL32(x1, 29) ^ x0;                  // r14
  x0 += x1;     x1 = ROTL32(x1, 16) ^ x0;                  // r15
  x0 += x1;     x1 = ROTL32(x1, 24) ^ x0;                  // r16
  t = x1 + kz4; x0 = x0 + ky + t; x1 = ROTL32(t, 13) ^ x0; // inj4 + r17
  x0 += x1;     x1 = ROTL32(x1, 15) ^ x0;                  // r18
  x0 += x1;     x1 = ROTL32(x1, 26) ^ x0;                  // r19
  x0 += x1;     x1 = ROTL32(x1,  6) ^ x0;                  // r20
  return (x0 + kz) ^ (x1 + kx5);                           // final inject + fold
}

#define WGL 1024
#define GL  16   // 16384 elems per WG -> 512 WGs

__global__ __launch_bounds__(WGL, 1) void fwd_diff_v6(
    const float* __restrict__ x_init,   // [8,1024,1024] fp32
    const float* __restrict__ dist,     // [8,65536] fp32
    float* __restrict__ out) {          // [8,1024,1024] fp32
  extern __shared__ char smem[];
  __half*   tab  = reinterpret_cast<__half*>(smem);            // 128 KB, Bc pre-folded fp16
  uint32_t* keys = reinterpret_cast<uint32_t*>(smem + 131072); // 2 KB step keys (k2 pairs)

  const int tid   = threadIdx.x;
  const int batch = blockIdx.x >> 6;    // 64 WGs per batch
  const int chunk = blockIdx.x & 63;
  const uint32_t base = ((uint32_t)batch << 20) + ((uint32_t)chunk << 14);

  const float Ac = 0.9899494936611665f;  // float32(sqrt(0.98))
  const float Bc = 0.1414213562373095f;  // float32(sqrt(0.02))

  // Stage Bc-folded fp16 table into LDS (vectorized: float4 in, ushort4 out).
  const float4* src = reinterpret_cast<const float4*>(dist + (size_t)batch * NDIST);
  for (int i = tid; i < NDIST / 4; i += WGL) {
    float4 v = src[i];
    ushort4 h;
    h.x = __half_as_ushort(__float2half(Bc * v.x));
    h.y = __half_as_ushort(__float2half(Bc * v.y));
    h.z = __half_as_ushort(__float2half(Bc * v.z));
    h.w = __half_as_ushort(__float2half(Bc * v.w));
    reinterpret_cast<ushort4*>(tab)[i] = h;
  }
  // Step keys (partitionable foldlike): k2 = TF(TF((0,42),(0,s)),(0,1)).
  if (tid < NSTEPS) {
    uint2 ks = threefry2x32(0u, 42u, 0x1BD11BDAu ^ 42u, 0u, (uint32_t)tid);
    uint2 k2 = threefry2x32(ks.x, ks.y, ks.x ^ ks.y ^ 0x1BD11BDAu, 0u, 1u);
    keys[2 * tid]     = k2.x;
    keys[2 * tid + 1] = k2.y;
  }
  __syncthreads();

  uint32_t p[GL];
  float acc[GL];
#pragma unroll
  for (int j = 0; j < GL; ++j) {
    p[j]   = base + (uint32_t)(j * WGL) + (uint32_t)tid;
    acc[j] = x_init[p[j]];
  }

  for (int s = 0; s < NSTEPS; ++s) {
    uint32_t kx = keys[2 * s];
    uint32_t ky = keys[2 * s + 1];
    kx = (uint32_t)__builtin_amdgcn_readfirstlane((int)kx);  // SGPR
    ky = (uint32_t)__builtin_amdgcn_readfirstlane((int)ky);
    const uint32_t kz  = kx ^ ky ^ 0x1BD11BDAu;
    const uint32_t kz1 = kz + 1u, kx2 = kx + 2u, ky3 = ky + 3u;  // SALU, co-issued
    const uint32_t kz4 = kz + 4u, kx5 = kx + 5u;

    uint32_t idx[GL];
#pragma unroll
    for (int j = 0; j < GL; ++j) {
      uint32_t v = draw_fold(kx, ky, kz, kz1, kx2, ky3, kz4, kx5, p[j]);
      idx[j] = v & 0xFFFFu;
    }
#pragma unroll
    for (int j = 0; j < GL; ++j) {
      acc[j] = fmaf(Ac, acc[j], __half2float(tab[idx[j]]));  // Bc folded in table
    }
  }

#pragma unroll
  for (int j = 0; j < GL; ++j) out[p[j]] = acc[j];
}

extern "C" void kernel_launch(void* const* d_in, const int* in_sizes, int n_in,
                              void* d_out, int out_size, void* d_ws, size_t ws_size,
                              hipStream_t stream) {
  const float* x_init = (const float*)d_in[0];
  const float* dist   = (const float*)d_in[1];
  if (n_in >= 2 && in_sizes[0] == 8 * NDIST) {  // defensive swap check
    x_init = (const float*)d_in[1];
    dist   = (const float*)d_in[0];
  }
  float* out = (float*)d_out;
  (void)d_ws; (void)ws_size;

  const int smem = 131072 + 2048;  // 128 KB table + 2 KB keys
  (void)hipFuncSetAttribute(reinterpret_cast<const void*>(fwd_diff_v6),
                            hipFuncAttributeMaxDynamicSharedMemorySize, smem);
  // 8 batches x 64 chunks; 16384 elems/WG (1024 thr x G=16).
  fwd_diff_v6<<<dim3(512), dim3(WGL), smem, stream>>>(x_init, dist, out);
}